// Round 2
// baseline (366.376 us; speedup 1.0000x reference)
//
#include <hip/hip_runtime.h>
#include <hip/hip_bf16.h>

#define BB 8
#define NN 4096
#define FF 128
#define DD 64
#define NB (BB*NN)           // 32768 rows total
#define CTCH 72              // channel stride in chunk-total table (65 used)
#define NCHK 64              // chunks per batch
#define PREROW 72            // floats per k-row in prefix table (65 used)
#define PREFAM ((NN+1)*PREROW)
#define PREB (2*PREFAM)

// workspace byte offsets
#define OFF_H    0                                   // float [NB][64]        8 MB
#define OFF_S1   (OFF_H    + (size_t)NB*DD*4)
#define OFF_S2   (OFF_S1   + (size_t)NB*4)
#define OFF_S2S  (OFF_S2   + (size_t)NB*4)
#define OFF_PERM (OFF_S2S  + (size_t)NB*4)
#define OFF_WPOS (OFF_PERM + (size_t)NB*4)
#define OFF_WNEG (OFF_WPOS + (size_t)NB*4)
#define OFF_CT   (OFF_WNEG + (size_t)NB*4)           // double [B][2][72][64] 576 KB
#define OFF_PRE  (OFF_CT   + (size_t)BB*2*CTCH*NCHK*8) // float [B][2][4097][72] ~18 MB

// ---------------- Kernel A: h = x @ W^T ; s1 = h.a1 ; s2 = h.a2 ----------------
__global__ __launch_bounds__(256) void gat_kA(const float* __restrict__ x,
                                              const float* __restrict__ W,
                                              const float* __restrict__ a,
                                              float* __restrict__ h,
                                              float* __restrict__ s1,
                                              float* __restrict__ s2) {
  __shared__ float xs[64][FF];
  const int tid  = threadIdx.x;
  const int lane = tid & 63;
  const int wave = tid >> 6;
  const long long rowbase = (long long)blockIdx.x * 64;

  const float4* x4  = (const float4*)(x + rowbase * FF);
  float4*       xs4 = (float4*)&xs[0][0];
#pragma unroll
  for (int i = 0; i < 8; ++i) xs4[tid + i * 256] = x4[tid + i * 256];

  float4 wreg[32];
  const float4* W4 = (const float4*)(W + lane * FF);
#pragma unroll
  for (int j = 0; j < 32; ++j) wreg[j] = W4[j];
  const float a1d = a[lane];
  const float a2d = a[DD + lane];
  __syncthreads();

  for (int r = wave * 16; r < wave * 16 + 16; ++r) {
    const float4* xr = (const float4*)&xs[r][0];
    float4 acc = {0.f, 0.f, 0.f, 0.f};
#pragma unroll
    for (int j = 0; j < 32; ++j) {
      float4 xv = xr[j];
      acc.x += xv.x * wreg[j].x;
      acc.y += xv.y * wreg[j].y;
      acc.z += xv.z * wreg[j].z;
      acc.w += xv.w * wreg[j].w;
    }
    float hd = (acc.x + acc.y) + (acc.z + acc.w);
    const long long row = rowbase + r;
    h[row * DD + lane] = hd;

    float p1 = hd * a1d, p2 = hd * a2d;
#pragma unroll
    for (int o = 32; o; o >>= 1) { p1 += __shfl_xor(p1, o); p2 += __shfl_xor(p2, o); }
    if (lane == 0) { s1[row] = p1; s2[row] = p2; }
  }
}

// ---------------- Kernel B: rank-by-counting sort of s2 (+perm), weight tables ----
// grid (16 tiles, 8 batches) x 256 threads. Full batch key array staged in LDS;
// every thread counts rank of its own key over 4096 LDS-broadcast reads
// (all lanes read the same key[i] -> HW broadcast, no bank conflicts).
__global__ __launch_bounds__(256) void gat_kB(const float* __restrict__ s2,
                                              float* __restrict__ s2s,
                                              int* __restrict__ perm,
                                              float* __restrict__ wpos,
                                              float* __restrict__ wneg) {
  __shared__ float key[NN];  // 16 KB
  const int b = blockIdx.y;
  const float* s2b = s2 + (size_t)b * NN;
  for (int i = threadIdx.x; i < NN; i += 256) key[i] = s2b[i];
  __syncthreads();

  const int j = blockIdx.x * 256 + threadIdx.x;
  const float mykey = key[j];
  int rank = 0;
  float mx = -3.4e38f;
#pragma unroll 8
  for (int i = 0; i < NN; ++i) {
    const float ki = key[i];
    if (ki < mykey || (ki == mykey && i < j)) ++rank;  // stable (key, idx) order
    mx = fmaxf(mx, ki);
  }
  const size_t o = (size_t)b * NN + rank;
  s2s[o]  = mykey;
  perm[o] = j;
  wpos[o] = expf(mykey - mx);           // <= 1
  wneg[o] = expf(0.2f * (mykey - mx));  // <= 1
}

// ---------------- Kernel C: per-chunk (64 j's) partial sums, fp64 ----------------
__global__ __launch_bounds__(64) void gat_kC(const float* __restrict__ h,
                                             const int* __restrict__ perm,
                                             const float* __restrict__ wpos,
                                             const float* __restrict__ wneg,
                                             double* __restrict__ CT) {
  const int c = blockIdx.x, b = blockIdx.y, d = threadIdx.x;
  const int base = b * NN + c * 64;
  double ap = 0, an = 0, zp = 0, zn = 0;
  for (int s = 0; s < 64; ++s) {
    const int j  = base + s;
    const int pj = perm[j];
    const float hv = h[((size_t)b * NN + pj) * DD + d];
    const float wp = wpos[j], wn = wneg[j];
    ap += (double)wp * hv; an += (double)wn * hv;
    zp += wp;              zn += wn;
  }
  double* CTb = CT + (size_t)b * 2 * CTCH * NCHK;
  CTb[(0 * CTCH + d) * NCHK + c] = an;
  CTb[(1 * CTCH + d) * NCHK + c] = ap;
  if (d == 0) {
    CTb[(0 * CTCH + 64) * NCHK + c] = zn;
    CTb[(1 * CTCH + 64) * NCHK + c] = zp;
  }
}

// ---------------- Kernel D: in-place exclusive scan of chunk totals ----------------
__global__ __launch_bounds__(256) void gat_kD(double* __restrict__ CT) {
  const int b = blockIdx.x, t = threadIdx.x;
  if (t >= 2 * CTCH) return;
  const int fam = t / CTCH, ch = t % CTCH;
  if (ch > 64) return;
  double* row = CT + ((size_t)b * 2 + fam) * CTCH * NCHK + (size_t)ch * NCHK;
  double off = 0;
  for (int c = 0; c < NCHK; ++c) { double v = row[c]; row[c] = off; off += v; }
}

// ---------------- Kernel E: fill full exclusive-prefix table PRE ----------------
__global__ __launch_bounds__(64) void gat_kE(const float* __restrict__ h,
                                             const int* __restrict__ perm,
                                             const float* __restrict__ wpos,
                                             const float* __restrict__ wneg,
                                             const double* __restrict__ CT,
                                             float* __restrict__ PRE) {
  const int c = blockIdx.x, b = blockIdx.y, d = threadIdx.x;
  const int base = b * NN + c * 64;
  const double* CTb = CT + (size_t)b * 2 * CTCH * NCHK;
  double an = CTb[(0 * CTCH + d) * NCHK + c];
  double ap = CTb[(1 * CTCH + d) * NCHK + c];
  double zn = CTb[(0 * CTCH + 64) * NCHK + c];
  double zp = CTb[(1 * CTCH + 64) * NCHK + c];
  float* PREb = PRE + (size_t)b * PREB;
  for (int s = 0; s < 64; ++s) {
    const int j = base + s;
    const int k = c * 64 + s;
    PREb[(size_t)(0 * (NN + 1) + k) * PREROW + d] = (float)an;
    PREb[(size_t)(1 * (NN + 1) + k) * PREROW + d] = (float)ap;
    if (d == 0) {
      PREb[(size_t)(0 * (NN + 1) + k) * PREROW + 64] = (float)zn;
      PREb[(size_t)(1 * (NN + 1) + k) * PREROW + 64] = (float)zp;
    }
    const int pj = perm[j];
    const float hv = h[((size_t)b * NN + pj) * DD + d];
    const float wp = wpos[j], wn = wneg[j];
    an += (double)wn * hv; ap += (double)wp * hv;
    zn += wn;              zp += wp;
  }
  if (c == NCHK - 1) {
    PREb[(size_t)(0 * (NN + 1) + NN) * PREROW + d] = (float)an;
    PREb[(size_t)(1 * (NN + 1) + NN) * PREROW + d] = (float)ap;
    if (d == 0) {
      PREb[(size_t)(0 * (NN + 1) + NN) * PREROW + 64] = (float)zn;
      PREb[(size_t)(1 * (NN + 1) + NN) * PREROW + 64] = (float)zp;
    }
  }
}

// ---------------- Kernel F: per-row binary search + combine + ELU ----------------
__global__ __launch_bounds__(256) void gat_kF(const float* __restrict__ s1,
                                              const float* __restrict__ s2s,
                                              const float* __restrict__ PRE,
                                              float* __restrict__ out) {
  const int tid = threadIdx.x, lane = tid & 63, wv = tid >> 6;
  const long long row = (long long)blockIdx.x * 4 + wv;   // 0..32767
  const int b = (int)(row >> 12);
  const float* s2b = s2s + (size_t)b * NN;

  const float s1i = s1[row];
  const float c1  = s2b[NN - 1];
  const float t   = -s1i;

  int lo = 0, hi = NN;
  while (lo < hi) { int mid = (lo + hi) >> 1; if (s2b[mid] <= t) lo = mid + 1; else hi = mid; }
  const int k = lo;

  const float z = s1i + c1;
  const float m = z >= 0.f ? z : 0.2f * z;
  const float A  = expf(z - m);
  const float Bn = expf(0.2f * z - m);

  const float* PREb = PRE + (size_t)b * PREB;
  const float* rowN = PREb + (size_t)(0 * (NN + 1) + k)  * PREROW;
  const float* rowP = PREb + (size_t)(1 * (NN + 1) + k)  * PREROW;
  const float* totP = PREb + (size_t)(1 * (NN + 1) + NN) * PREROW;

  const float pre_d = rowN[lane];
  const float suf_d = totP[lane] - rowP[lane];
  const float Zpre  = rowN[64];
  const float Zsuf  = totP[64] - rowP[64];

  const float num = A * suf_d + Bn * pre_d;
  const float Z   = A * Zsuf  + Bn * Zpre;
  const float hp  = num / Z;
  out[row * DD + lane] = hp > 0.f ? hp : expm1f(hp);
}

extern "C" void kernel_launch(void* const* d_in, const int* in_sizes, int n_in,
                              void* d_out, int out_size, void* d_ws, size_t ws_size,
                              hipStream_t stream) {
  const float* x = (const float*)d_in[0];
  const float* W = (const float*)d_in[1];
  const float* a = (const float*)d_in[2];
  float* out = (float*)d_out;

  char* ws = (char*)d_ws;
  float*  h    = (float*)(ws + OFF_H);
  float*  s1   = (float*)(ws + OFF_S1);
  float*  s2   = (float*)(ws + OFF_S2);
  float*  s2s  = (float*)(ws + OFF_S2S);
  int*    perm = (int*)  (ws + OFF_PERM);
  float*  wpos = (float*)(ws + OFF_WPOS);
  float*  wneg = (float*)(ws + OFF_WNEG);
  double* CT   = (double*)(ws + OFF_CT);
  float*  PRE  = (float*)(ws + OFF_PRE);

  gat_kA<<<NB / 64, 256, 0, stream>>>(x, W, a, h, s1, s2);
  gat_kB<<<dim3(NN / 256, BB), 256, 0, stream>>>(s2, s2s, perm, wpos, wneg);
  gat_kC<<<dim3(NCHK, BB), 64, 0, stream>>>(h, perm, wpos, wneg, CT);
  gat_kD<<<BB, 256, 0, stream>>>(CT);
  gat_kE<<<dim3(NCHK, BB), 64, 0, stream>>>(h, perm, wpos, wneg, CT, PRE);
  gat_kF<<<NB / 4, 256, 0, stream>>>(s1, s2s, PRE, out);
}

// Round 3
// 102.208 us; speedup vs baseline: 3.5846x; 3.5846x over previous
//
#include <hip/hip_runtime.h>
#include <hip/hip_bf16.h>

#define BB 8
#define NN 4096
#define FF 128
#define DD 64
#define NB (BB*NN)           // 32768 rows total
#define CTCH 72              // channel stride in chunk-total table (65 used)
#define NCHK 64              // chunks per batch (kernels C/E)
#define PREROW 72            // floats per k-row in prefix table (65 used)
#define PREFAM ((NN+1)*PREROW)
#define PREB (2*PREFAM)
#define CHK 128              // i-chunk size for rank kernel
#define NCH (NN/CHK)         // 32 rank chunks per batch

// workspace byte offsets
#define OFF_H     0                                    // float [NB][64]        8 MB
#define OFF_S1    (OFF_H    + (size_t)NB*DD*4)
#define OFF_S2    (OFF_S1   + (size_t)NB*4)
#define OFF_S2S   (OFF_S2   + (size_t)NB*4)
#define OFF_PERM  (OFF_S2S  + (size_t)NB*4)
#define OFF_WPOS  (OFF_PERM + (size_t)NB*4)
#define OFF_WNEG  (OFF_WPOS + (size_t)NB*4)
#define OFF_CT    (OFF_WNEG + (size_t)NB*4)            // double [B][2][72][64] 576 KB
#define OFF_PRE   (OFF_CT   + (size_t)BB*2*CTCH*NCHK*8)  // float [B][2][4097][72] ~19 MB
#define OFF_PRANK (OFF_PRE  + (size_t)BB*PREB*4)       // u16 [32][B][4096]     2 MB

// monotone float->u32 map (IEEE total order for non-NaN)
__device__ __forceinline__ unsigned int fkey(float f) {
  unsigned int u = __float_as_uint(f);
  return (u & 0x80000000u) ? ~u : (u | 0x80000000u);
}

// ---------------- Kernel A: h = x @ W^T ; s1 = h.a1 ; s2 = h.a2 ----------------
__global__ __launch_bounds__(256) void gat_kA(const float* __restrict__ x,
                                              const float* __restrict__ W,
                                              const float* __restrict__ a,
                                              float* __restrict__ h,
                                              float* __restrict__ s1,
                                              float* __restrict__ s2) {
  __shared__ float xs[64][FF];
  const int tid  = threadIdx.x;
  const int lane = tid & 63;
  const int wave = tid >> 6;
  const long long rowbase = (long long)blockIdx.x * 64;

  const float4* x4  = (const float4*)(x + rowbase * FF);
  float4*       xs4 = (float4*)&xs[0][0];
#pragma unroll
  for (int i = 0; i < 8; ++i) xs4[tid + i * 256] = x4[tid + i * 256];

  float4 wreg[32];
  const float4* W4 = (const float4*)(W + lane * FF);
#pragma unroll
  for (int j = 0; j < 32; ++j) wreg[j] = W4[j];
  const float a1d = a[lane];
  const float a2d = a[DD + lane];
  __syncthreads();

  for (int r = wave * 16; r < wave * 16 + 16; ++r) {
    const float4* xr = (const float4*)&xs[r][0];
    float4 acc = {0.f, 0.f, 0.f, 0.f};
#pragma unroll
    for (int j = 0; j < 32; ++j) {
      float4 xv = xr[j];
      acc.x += xv.x * wreg[j].x;
      acc.y += xv.y * wreg[j].y;
      acc.z += xv.z * wreg[j].z;
      acc.w += xv.w * wreg[j].w;
    }
    float hd = (acc.x + acc.y) + (acc.z + acc.w);
    const long long row = rowbase + r;
    h[row * DD + lane] = hd;

    float p1 = hd * a1d, p2 = hd * a2d;
#pragma unroll
    for (int o = 32; o; o >>= 1) { p1 += __shfl_xor(p1, o); p2 += __shfl_xor(p2, o); }
    if (lane == 0) { s1[row] = p1; s2[row] = p2; }
  }
}

// ---------------- Kernel B1: partial ranks, register-blocked ----------------
// grid (32 i-chunks, 8 batches) x 256. Each thread owns 16 j-keys in VGPRs;
// one broadcast ds_read_b64 of K_i feeds 16 u64-compares (2 VALU insts each).
__global__ __launch_bounds__(256) void gat_kB1(const float* __restrict__ s2,
                                               unsigned short* __restrict__ prank) {
  __shared__ unsigned long long ks[CHK];
  const int c = blockIdx.x, b = blockIdx.y, tid = threadIdx.x;
  const float* s2b = s2 + (size_t)b * NN;

  if (tid < CHK) {
    const int ig = c * CHK + tid;
    ks[tid] = ((unsigned long long)fkey(s2b[ig]) << 12) | (unsigned)ig;
  }

  unsigned long long kj[16];
  int rank[16];
#pragma unroll
  for (int t = 0; t < 16; ++t) {
    const int j = tid + 256 * t;                    // coalesced
    kj[t] = ((unsigned long long)fkey(s2b[j]) << 12) | (unsigned)j;
    rank[t] = 0;
  }
  __syncthreads();

#pragma unroll 4
  for (int i = 0; i < CHK; ++i) {
    const unsigned long long ki = ks[i];            // LDS broadcast
#pragma unroll
    for (int t = 0; t < 16; ++t) rank[t] += (ki < kj[t]) ? 1 : 0;
  }

  unsigned short* pr = prank + ((size_t)c * BB + b) * NN;
#pragma unroll
  for (int t = 0; t < 16; ++t) pr[tid + 256 * t] = (unsigned short)rank[t];
}

// ---------------- Kernel B2: sum partials, batch max, scatter + exp tables ------
__global__ __launch_bounds__(256) void gat_kB2(const float* __restrict__ s2,
                                               const unsigned short* __restrict__ prank,
                                               float* __restrict__ s2s,
                                               int* __restrict__ perm,
                                               float* __restrict__ wpos,
                                               float* __restrict__ wneg) {
  __shared__ float red[4];
  const int b = blockIdx.y, tid = threadIdx.x;
  const int j = blockIdx.x * 256 + tid;
  const float* s2b = s2 + (size_t)b * NN;

  float mx = -3.4e38f;
  for (int i = tid; i < NN; i += 256) mx = fmaxf(mx, s2b[i]);
#pragma unroll
  for (int o = 32; o; o >>= 1) mx = fmaxf(mx, __shfl_xor(mx, o));
  if ((tid & 63) == 0) red[tid >> 6] = mx;
  __syncthreads();
  mx = fmaxf(fmaxf(red[0], red[1]), fmaxf(red[2], red[3]));

  int rank = 0;
#pragma unroll 8
  for (int c = 0; c < NCH; ++c) rank += prank[((size_t)c * BB + b) * NN + j];

  const float key = s2b[j];
  const size_t o = (size_t)b * NN + rank;
  s2s[o]  = key;
  perm[o] = j;
  wpos[o] = expf(key - mx);           // <= 1
  wneg[o] = expf(0.2f * (key - mx));  // <= 1
}

// ---------------- Kernel C: per-chunk (64 j's) partial sums, fp64 ----------------
__global__ __launch_bounds__(64) void gat_kC(const float* __restrict__ h,
                                             const int* __restrict__ perm,
                                             const float* __restrict__ wpos,
                                             const float* __restrict__ wneg,
                                             double* __restrict__ CT) {
  const int c = blockIdx.x, b = blockIdx.y, d = threadIdx.x;
  const int base = b * NN + c * 64;
  double ap = 0, an = 0, zp = 0, zn = 0;
  for (int s = 0; s < 64; ++s) {
    const int j  = base + s;
    const int pj = perm[j];
    const float hv = h[((size_t)b * NN + pj) * DD + d];
    const float wp = wpos[j], wn = wneg[j];
    ap += (double)wp * hv; an += (double)wn * hv;
    zp += wp;              zn += wn;
  }
  double* CTb = CT + (size_t)b * 2 * CTCH * NCHK;
  CTb[(0 * CTCH + d) * NCHK + c] = an;
  CTb[(1 * CTCH + d) * NCHK + c] = ap;
  if (d == 0) {
    CTb[(0 * CTCH + 64) * NCHK + c] = zn;
    CTb[(1 * CTCH + 64) * NCHK + c] = zp;
  }
}

// ---------------- Kernel D: in-place exclusive scan of chunk totals ----------------
__global__ __launch_bounds__(256) void gat_kD(double* __restrict__ CT) {
  const int b = blockIdx.x, t = threadIdx.x;
  if (t >= 2 * CTCH) return;
  const int fam = t / CTCH, ch = t % CTCH;
  if (ch > 64) return;
  double* row = CT + ((size_t)b * 2 + fam) * CTCH * NCHK + (size_t)ch * NCHK;
  double off = 0;
  for (int c = 0; c < NCHK; ++c) { double v = row[c]; row[c] = off; off += v; }
}

// ---------------- Kernel E: fill full exclusive-prefix table PRE ----------------
__global__ __launch_bounds__(64) void gat_kE(const float* __restrict__ h,
                                             const int* __restrict__ perm,
                                             const float* __restrict__ wpos,
                                             const float* __restrict__ wneg,
                                             const double* __restrict__ CT,
                                             float* __restrict__ PRE) {
  const int c = blockIdx.x, b = blockIdx.y, d = threadIdx.x;
  const int base = b * NN + c * 64;
  const double* CTb = CT + (size_t)b * 2 * CTCH * NCHK;
  double an = CTb[(0 * CTCH + d) * NCHK + c];
  double ap = CTb[(1 * CTCH + d) * NCHK + c];
  double zn = CTb[(0 * CTCH + 64) * NCHK + c];
  double zp = CTb[(1 * CTCH + 64) * NCHK + c];
  float* PREb = PRE + (size_t)b * PREB;
  for (int s = 0; s < 64; ++s) {
    const int j = base + s;
    const int k = c * 64 + s;
    PREb[(size_t)(0 * (NN + 1) + k) * PREROW + d] = (float)an;
    PREb[(size_t)(1 * (NN + 1) + k) * PREROW + d] = (float)ap;
    if (d == 0) {
      PREb[(size_t)(0 * (NN + 1) + k) * PREROW + 64] = (float)zn;
      PREb[(size_t)(1 * (NN + 1) + k) * PREROW + 64] = (float)zp;
    }
    const int pj = perm[j];
    const float hv = h[((size_t)b * NN + pj) * DD + d];
    const float wp = wpos[j], wn = wneg[j];
    an += (double)wn * hv; ap += (double)wp * hv;
    zn += wn;              zp += wp;
  }
  if (c == NCHK - 1) {
    PREb[(size_t)(0 * (NN + 1) + NN) * PREROW + d] = (float)an;
    PREb[(size_t)(1 * (NN + 1) + NN) * PREROW + d] = (float)ap;
    if (d == 0) {
      PREb[(size_t)(0 * (NN + 1) + NN) * PREROW + 64] = (float)zn;
      PREb[(size_t)(1 * (NN + 1) + NN) * PREROW + 64] = (float)zp;
    }
  }
}

// ---------------- Kernel F: per-row binary search + combine + ELU ----------------
__global__ __launch_bounds__(256) void gat_kF(const float* __restrict__ s1,
                                              const float* __restrict__ s2s,
                                              const float* __restrict__ PRE,
                                              float* __restrict__ out) {
  const int tid = threadIdx.x, lane = tid & 63, wv = tid >> 6;
  const long long row = (long long)blockIdx.x * 4 + wv;   // 0..32767
  const int b = (int)(row >> 12);
  const float* s2b = s2s + (size_t)b * NN;

  const float s1i = s1[row];
  const float c1  = s2b[NN - 1];
  const float t   = -s1i;

  int lo = 0, hi = NN;
  while (lo < hi) { int mid = (lo + hi) >> 1; if (s2b[mid] <= t) lo = mid + 1; else hi = mid; }
  const int k = lo;

  const float z = s1i + c1;
  const float m = z >= 0.f ? z : 0.2f * z;
  const float A  = expf(z - m);
  const float Bn = expf(0.2f * z - m);

  const float* PREb = PRE + (size_t)b * PREB;
  const float* rowN = PREb + (size_t)(0 * (NN + 1) + k)  * PREROW;
  const float* rowP = PREb + (size_t)(1 * (NN + 1) + k)  * PREROW;
  const float* totP = PREb + (size_t)(1 * (NN + 1) + NN) * PREROW;

  const float pre_d = rowN[lane];
  const float suf_d = totP[lane] - rowP[lane];
  const float Zpre  = rowN[64];
  const float Zsuf  = totP[64] - rowP[64];

  const float num = A * suf_d + Bn * pre_d;
  const float Z   = A * Zsuf  + Bn * Zpre;
  const float hp  = num / Z;
  out[row * DD + lane] = hp > 0.f ? hp : expm1f(hp);
}

extern "C" void kernel_launch(void* const* d_in, const int* in_sizes, int n_in,
                              void* d_out, int out_size, void* d_ws, size_t ws_size,
                              hipStream_t stream) {
  const float* x = (const float*)d_in[0];
  const float* W = (const float*)d_in[1];
  const float* a = (const float*)d_in[2];
  float* out = (float*)d_out;

  char* ws = (char*)d_ws;
  float*  h    = (float*)(ws + OFF_H);
  float*  s1   = (float*)(ws + OFF_S1);
  float*  s2   = (float*)(ws + OFF_S2);
  float*  s2s  = (float*)(ws + OFF_S2S);
  int*    perm = (int*)  (ws + OFF_PERM);
  float*  wpos = (float*)(ws + OFF_WPOS);
  float*  wneg = (float*)(ws + OFF_WNEG);
  double* CT   = (double*)(ws + OFF_CT);
  float*  PRE  = (float*)(ws + OFF_PRE);
  unsigned short* prank = (unsigned short*)(ws + OFF_PRANK);

  gat_kA<<<NB / 64, 256, 0, stream>>>(x, W, a, h, s1, s2);
  gat_kB1<<<dim3(NCH, BB), 256, 0, stream>>>(s2, prank);
  gat_kB2<<<dim3(NN / 256, BB), 256, 0, stream>>>(s2, prank, s2s, perm, wpos, wneg);
  gat_kC<<<dim3(NCHK, BB), 64, 0, stream>>>(h, perm, wpos, wneg, CT);
  gat_kD<<<BB, 256, 0, stream>>>(CT);
  gat_kE<<<dim3(NCHK, BB), 64, 0, stream>>>(h, perm, wpos, wneg, CT, PRE);
  gat_kF<<<NB / 4, 256, 0, stream>>>(s1, s2s, PRE, out);
}